// Round 8
// baseline (363.819 us; speedup 1.0000x reference)
//
#include <hip/hip_runtime.h>
#include <math.h>

#define B_ 4
#define C_ 128
#define N_ 4096
#define NSPLIT 4
#define MT 32     // keys per iteration
#define PLD 40    // Ps row stride (shorts): 32 + 8 pad (80 B, 16B-divisible)
#define HLD 136   // h/q/k tile row stride (shorts): 128 + 8 pad
#define VTLD 40   // v-tile row stride (shorts): 32 + 8 pad
#define NBLK 512u

typedef float floatx4 __attribute__((ext_vector_type(4)));
typedef short bf16x8 __attribute__((ext_vector_type(8)));

__device__ __forceinline__ ushort f2bf(float f) {  // RNE
  unsigned u = __float_as_uint(f);
  return (ushort)((u + 0x7FFF + ((u >> 16) & 1)) >> 16);
}
__device__ __forceinline__ float bf2f(ushort u) {
  return __uint_as_float(((unsigned)u) << 16);
}
__device__ __forceinline__ unsigned pkbf(float a, float b) {
  return __builtin_amdgcn_perm(__float_as_uint(a) + 0x8000u,
                               __float_as_uint(b) + 0x8000u, 0x07060302u);
}
__device__ __forceinline__ float fexp2(float x) {
#if __has_builtin(__builtin_amdgcn_exp2f)
  return __builtin_amdgcn_exp2f(x);
#else
  return exp2f(x);
#endif
}
__device__ __forceinline__ void gl2lds16(const ushort* g, ushort* l) {
  __builtin_amdgcn_global_load_lds(
      (const __attribute__((address_space(1))) void*)g,
      (__attribute__((address_space(3))) void*)l, 16, 0, 0);
}

// Software grid barrier (sense-reversing).  bar[0]=count, bar[1]=generation.
// Works under a NORMAL launch (graph-capture safe) because grid=512 is exactly
// 2 blocks/CU x 256 CUs co-resident (LDS 54272B and VGPR<=128 both give 2/CU).
// Agent-scope acq/rel gives cross-XCD visibility (L2 wb/inv at the fence).
// Happens-before chain: every block's count-RMW (ACQ_REL) -> last arriver's
// count-RMW acquire -> its gen-RMW release -> spinners' gen acquire.
__device__ __forceinline__ void grid_bar(unsigned* bar) {
  __syncthreads();
  if (threadIdx.x == 0) {
    unsigned gen = __hip_atomic_load(&bar[1], __ATOMIC_RELAXED, __HIP_MEMORY_SCOPE_AGENT);
    unsigned prev = __hip_atomic_fetch_add(&bar[0], 1u, __ATOMIC_ACQ_REL, __HIP_MEMORY_SCOPE_AGENT);
    if (prev + 1u == NBLK) {
      __hip_atomic_store(&bar[0], 0u, __ATOMIC_RELAXED, __HIP_MEMORY_SCOPE_AGENT);
      __hip_atomic_fetch_add(&bar[1], 1u, __ATOMIC_RELEASE, __HIP_MEMORY_SCOPE_AGENT);
    } else {
      while (__hip_atomic_load(&bar[1], __ATOMIC_ACQUIRE, __HIP_MEMORY_SCOPE_AGENT) == gen)
        __builtin_amdgcn_s_sleep(2);
    }
  }
  __syncthreads();
}

// =====================================================================================
// ONE kernel, 4 phases separated by software grid barriers.  grid 512 x 512 thr,
// 54,272 B LDS (attn footprint; overlaid per phase), launch_bounds(512,4).
// Phase roles per block (bx = 0..511):
//   P0: bx<256 -> gn-stats task (b,g,part); bx>=256 -> weight bf16 convert.
//   P1: gnqkv, (b, 32-n tile) = (bx>>7, bx&127).  8 waves x 16 out-ch.
//   P2: attn (R3/R6-identical structure), sp=bx&3, qblk=(bx>>2)&31, b=bx>>7.
//   P3: mergeproj, (b, 32-n tile).  8 waves x 16 out-ch.
// =====================================================================================
__global__ __launch_bounds__(512, 4) void fused_kernel(
    const float* __restrict__ x, const float* __restrict__ gn_scale,
    const float* __restrict__ gn_bias,
    const float* __restrict__ wq, const float* __restrict__ bq,
    const float* __restrict__ wk, const float* __restrict__ bk,
    const float* __restrict__ wv, const float* __restrict__ bv,
    const float* __restrict__ wp, const float* __restrict__ bp,
    float* __restrict__ out, unsigned* __restrict__ bar,
    float* __restrict__ Lv, ushort* __restrict__ wB,
    float* __restrict__ gstat, ushort* __restrict__ qT, ushort* __restrict__ kT,
    ushort* __restrict__ vB, ushort* __restrict__ Op) {
  __shared__ __align__(16) char smem[54272];
  ushort* sm_u = (ushort*)smem;
  int bx = blockIdx.x;
  int tid = threadIdx.x, lane = tid & 63, w = tid >> 6;
  int col = lane & 15, quad = lane >> 4;

  // ---------------- P0: gn stats + weight convert ----------------
  if (bx >= 256) {   // weight convert: 65536 elems over 256 blocks
    if (tid < 256) {
      int i = (bx - 256) * 256 + tid;
      int m = i >> 14, j = i & 16383;
      const float* src = (m == 0) ? wq : (m == 1) ? wk : (m == 2) ? wv : wp;
      wB[i] = f2bf(src[j]);
    }
  } else {
    int b = bx >> 6, g = (bx >> 3) & 7, part = bx & 7;
    const float4* xp = (const float4*)(x + (size_t)(b * C_ + g * 16) * N_) + part * 2048;
    float s = 0.f, ss = 0.f;
    for (int i = tid; i < 2048; i += 512) {
      float4 v = xp[i];
      s += v.x + v.y + v.z + v.w;
      ss += v.x * v.x + v.y * v.y + v.z * v.z + v.w * v.w;
    }
    #pragma unroll
    for (int o = 32; o > 0; o >>= 1) {
      s += __shfl_down(s, o, 64);
      ss += __shfl_down(ss, o, 64);
    }
    float* rs = (float*)smem;        // 8 floats
    float* rss = (float*)smem + 8;   // 8 floats
    if (lane == 0) { rs[w] = s; rss[w] = ss; }
    __syncthreads();
    if (tid == 0) {
      float S = 0.f, SS = 0.f;
      #pragma unroll
      for (int k = 0; k < 8; ++k) { S += rs[k]; SS += rss[k]; }
      int slot = (b * 8 + g) * 8 + part;
      gstat[slot]       = S;
      gstat[256 + slot] = SS;
    }
  }
  grid_bar(bar);

  // ---------------- P1: GN-apply + QKV MFMA ----------------
  {
    ushort* hs = sm_u;               // [32][HLD]   8704 B
    ushort* Qt = sm_u + 4352;        // [32][HLD]
    ushort* Kt = sm_u + 8704;        // [32][HLD]
    ushort* Vt = sm_u + 13056;       // [128][VTLD] 10240 B
    float* sSc = (float*)(smem + 36352);
    float* sBi = (float*)(smem + 36864);
    int b = bx >> 7;
    int n0 = (bx & 127) * 32;
    if (tid < 128) {
      int g = tid >> 4;
      float S = 0.f, SS = 0.f;
      #pragma unroll
      for (int p = 0; p < 8; ++p) {
        S  += gstat[(b * 8 + g) * 8 + p];
        SS += gstat[256 + (b * 8 + g) * 8 + p];
      }
      float mu = S * (1.f / 65536.f);
      float var = SS * (1.f / 65536.f) - mu * mu;
      float rstd = rsqrtf(var + 1e-6f);
      float sc = gn_scale[tid] * rstd;
      sSc[tid] = sc;
      sBi[tid] = gn_bias[tid] - mu * sc;
    }
    __syncthreads();
    #pragma unroll
    for (int k2 = 0; k2 < 2; ++k2) {   // 128 c x 8 float4 (32 n) = 1024
      int i = tid + k2 * 512;
      int c = i >> 3, n4 = i & 7;
      float4 v = *(const float4*)(x + (size_t)(b * C_ + c) * N_ + n0 + n4 * 4);
      float sc = sSc[c], bi = sBi[c];
      hs[(n4 * 4 + 0) * HLD + c] = f2bf(v.x * sc + bi);
      hs[(n4 * 4 + 1) * HLD + c] = f2bf(v.y * sc + bi);
      hs[(n4 * 4 + 2) * HLD + c] = f2bf(v.z * sc + bi);
      hs[(n4 * 4 + 3) * HLD + c] = f2bf(v.w * sc + bi);
    }
    __syncthreads();
    int o0 = w * 16;   // 8 waves x 16 output channels
    bf16x8 hf[2][4];   // [n-half][kc]
    #pragma unroll
    for (int nh = 0; nh < 2; ++nh)
      #pragma unroll
      for (int kc = 0; kc < 4; ++kc)
        hf[nh][kc] = *(const bf16x8*)&hs[(nh * 16 + col) * HLD + kc * 32 + quad * 8];
    const ushort* Wq = wB;
    const ushort* Wk = wB + 16384;
    const ushort* Wv = wB + 32768;
    const float scl = 0.12751879752224991f;  // 128^-0.5 * log2(e)
    floatx4 aq[2] = {(floatx4)0.f, (floatx4)0.f};
    floatx4 ak[2] = {(floatx4)0.f, (floatx4)0.f};
    floatx4 av[2] = {(floatx4)0.f, (floatx4)0.f};
    #pragma unroll
    for (int kc = 0; kc < 4; ++kc) {
      int wo = (o0 + col) * C_ + kc * 32 + quad * 8;
      bf16x8 wqf = *(const bf16x8*)&Wq[wo];
      bf16x8 wkf = *(const bf16x8*)&Wk[wo];
      bf16x8 wvf = *(const bf16x8*)&Wv[wo];
      #pragma unroll
      for (int nh = 0; nh < 2; ++nh) {
        aq[nh] = __builtin_amdgcn_mfma_f32_16x16x32_bf16(wqf, hf[nh][kc], aq[nh], 0, 0, 0);
        ak[nh] = __builtin_amdgcn_mfma_f32_16x16x32_bf16(wkf, hf[nh][kc], ak[nh], 0, 0, 0);
        av[nh] = __builtin_amdgcn_mfma_f32_16x16x32_bf16(wvf, hf[nh][kc], av[nh], 0, 0, 0);
      }
    }
    float4 bqv = *(const float4*)&bq[o0 + quad * 4];
    float4 bkv = *(const float4*)&bk[o0 + quad * 4];
    float4 bvv = *(const float4*)&bv[o0 + quad * 4];
    #pragma unroll
    for (int nh = 0; nh < 2; ++nh) {
      uint2 qs = { pkbf((aq[nh][1] + bqv.y) * scl, (aq[nh][0] + bqv.x) * scl),
                   pkbf((aq[nh][3] + bqv.w) * scl, (aq[nh][2] + bqv.z) * scl) };
      uint2 ks = { pkbf(ak[nh][1] + bkv.y, ak[nh][0] + bkv.x),
                   pkbf(ak[nh][3] + bkv.w, ak[nh][2] + bkv.z) };
      *(uint2*)&Qt[(nh * 16 + col) * HLD + o0 + quad * 4] = qs;
      *(uint2*)&Kt[(nh * 16 + col) * HLD + o0 + quad * 4] = ks;
      float vv[4] = {av[nh][0] + bvv.x, av[nh][1] + bvv.y,
                     av[nh][2] + bvv.z, av[nh][3] + bvv.w};
      #pragma unroll
      for (int r = 0; r < 4; ++r)
        Vt[(o0 + quad * 4 + r) * VTLD + nh * 16 + col] = f2bf(vv[r]);
    }
    __syncthreads();
    {
      int row = tid >> 4, seg = tid & 15;   // 32 rows x 16 segs
      size_t dst = ((size_t)b * N_ + n0 + row) * C_ + seg * 8;
      *(uint4*)(qT + dst) = *(const uint4*)&Qt[row * HLD + seg * 8];
      *(uint4*)(kT + dst) = *(const uint4*)&Kt[row * HLD + seg * 8];
    }
    {
      int o = tid >> 2, seg = tid & 3;      // 128 ch x 4 segs
      *(uint4*)(vB + ((size_t)b * C_ + o) * N_ + n0 + seg * 8) =
          *(const uint4*)&Vt[o * VTLD + seg * 8];
    }
  }
  grid_bar(bar);

  // ---------------- P2: flash attention (R3/R6 structure, flat LDS) ----------------
  {
    ushort* Ks = sm_u;            // [2][4096] shorts (chunk-swizzled by row&7)
    ushort* Vs = sm_u + 8192;     // [2][4096] shorts (chunk-swizzled by (c>>1)&3)
    ushort* Ps = sm_u + 16384;    // [2][5120] shorts, double-buffered
    float* lpart = (float*)(smem + 53248);  // [8][2][16]
    int sp = bx & 3;
    int qblk = (bx >> 2) & 31;
    int b = bx >> 7;
    int n0 = qblk * 128;
    int wu = __builtin_amdgcn_readfirstlane(w);
    int mtw = w & 1, qg = w >> 1;   // S-phase roles
    int qh = w & 1, cq = w >> 1;    // PV-phase roles
    const ushort* kTb = kT + (size_t)b * N_ * C_;
    const ushort* vBb = vB + (size_t)b * C_ * N_;

    bf16x8 qf[2][4];
    #pragma unroll
    for (int qt = 0; qt < 2; ++qt)
      #pragma unroll
      for (int kc = 0; kc < 4; ++kc)
        qf[qt][kc] = *(const bf16x8*)(qT + ((size_t)b * N_ + n0 + qg * 32 + qt * 16 + col) * C_ + kc * 32 + quad * 8);

    floatx4 Oacc[4][2];
    #pragma unroll
    for (int qt = 0; qt < 4; ++qt)
      #pragma unroll
      for (int ct = 0; ct < 2; ++ct) Oacc[qt][ct] = (floatx4)0.f;
    float lacc[2] = {0.f, 0.f};

    const int m00 = sp * 1024;
    const ushort* kgp;
    const ushort* vgp;
    {
      int r = wu * 4 + (lane >> 4);
      int pos = (lane & 15) ^ (r & 7);
      kgp = kTb + (size_t)(m00 + r) * 128 + pos * 8;
      int c = wu * 16 + (lane >> 2);
      int mc = (lane & 3) ^ ((lane >> 3) & 3);
      vgp = vBb + (size_t)c * N_ + m00 + mc * 8;
    }

    #define STAGE(buf)                                        \
      {                                                       \
        gl2lds16(kgp, Ks + (buf)*4096 + wu * 512);            \
        gl2lds16(vgp, Vs + (buf)*4096 + wu * 512);            \
        kgp += MT * 128;                                      \
        vgp += MT;                                            \
      }

    #define S_COMPUTE(KsB, st)                                                          \
      {                                                                                 \
        int row = mtw * 16 + col;                                                       \
        bf16x8 kf[4];                                                                   \
        _Pragma("unroll")                                                               \
        for (int kc = 0; kc < 4; ++kc)                                                  \
          kf[kc] = *(const bf16x8*)&(KsB)[row * 128 + (((4 * kc + quad) ^ (col & 7)) * 8)]; \
        __builtin_amdgcn_s_setprio(1);                                                  \
        _Pragma("unroll")                                                               \
        for (int qt = 0; qt < 2; ++qt) {                                                \
          floatx4 acc = (floatx4)0.f;                                                   \
          _Pragma("unroll")                                                             \
          for (int kc = 0; kc < 4; ++kc)                                                \
            acc = __builtin_amdgcn_mfma_f32_16x16x32_bf16(kf[kc], qf[qt][kc], acc, 0, 0, 0); \
          st[qt] = acc;                                                                 \
        }                                                                               \
        __builtin_amdgcn_s_setprio(0);                                                  \
      }

    #define SOFTMAX_WRITE(PsB, st)                                                      \
      {                                                                                 \
        _Pragma("unroll")                                                               \
        for (int qt = 0; qt < 2; ++qt) {                                                \
          int prow = (qg * 32 + qt * 16 + col) * PLD + mtw * 16;                        \
          float p0 = fexp2(st[qt][0]);                                                  \
          float p1 = fexp2(st[qt][1]);                                                  \
          float p2 = fexp2(st[qt][2]);                                                  \
          float p3 = fexp2(st[qt][3]);                                                  \
          uint2 pk = { pkbf(p1, p0), pkbf(p3, p2) };                                    \
          *(uint2*)&(PsB)[prow + quad * 4] = pk;                                        \
          lacc[qt] += (p0 + p1) + (p2 + p3);                                            \
        }                                                                               \
      }

    #define V_LOAD(VsB, vfp)                                                            \
      {                                                                                 \
        _Pragma("unroll")                                                               \
        for (int ct = 0; ct < 2; ++ct)                                                  \
          vfp[ct] = *(const bf16x8*)&(VsB)[(cq * 32 + ct * 16 + col) * MT +             \
                                           ((quad ^ ((col >> 1) & 3)) * 8)];            \
      }

    #define PV_COMPUTE(PsB, vfp)                                                        \
      {                                                                                 \
        __builtin_amdgcn_s_setprio(1);                                                  \
        _Pragma("unroll")                                                               \
        for (int qt = 0; qt < 4; ++qt) {                                                \
          bf16x8 pf = *(const bf16x8*)&(PsB)[(qh * 64 + qt * 16 + col) * PLD + quad * 8]; \
          _Pragma("unroll")                                                             \
          for (int ct = 0; ct < 2; ++ct)                                                \
            Oacc[qt][ct] = __builtin_amdgcn_mfma_f32_16x16x32_bf16(pf, vfp[ct], Oacc[qt][ct], 0, 0, 0); \
        }                                                                               \
        __builtin_amdgcn_s_setprio(0);                                                  \
      }

    floatx4 st[2];
    bf16x8 vfp[2];

    STAGE(0);
    __syncthreads();

    // t = 0 (no PV yet)
    STAGE(1);
    S_COMPUTE(Ks, st);
    SOFTMAX_WRITE(Ps, st);
    V_LOAD(Vs, vfp);
    __syncthreads();

    // steady state t = 1..30: S(t) ; PV(t-1) ; softmax(t) ; vload(t) ; barrier
    for (int t = 1; t < 31; ++t) {
      STAGE((t + 1) & 1);
      S_COMPUTE(Ks + (t & 1) * 4096, st);
      PV_COMPUTE(Ps + ((t - 1) & 1) * 5120, vfp);
      SOFTMAX_WRITE(Ps + (t & 1) * 5120, st);
      V_LOAD(Vs + (t & 1) * 4096, vfp);
      __syncthreads();
    }

    // t = 31 (no stage)
    S_COMPUTE(Ks + 4096, st);
    PV_COMPUTE(Ps, vfp);
    SOFTMAX_WRITE(Ps + 5120, st);
    V_LOAD(Vs + 4096, vfp);
    __syncthreads();

    // drain PV(31)
    PV_COMPUTE(Ps + 5120, vfp);

    // epilogue: Op[sp][b][n][c] bf16 (unnormalized)
    ushort* OpB = Op + (((size_t)sp * B_ + b) * N_ + n0) * C_;
    #pragma unroll
    for (int qt = 0; qt < 4; ++qt)
      #pragma unroll
      for (int ct = 0; ct < 2; ++ct)
        #pragma unroll
        for (int r = 0; r < 4; ++r)
          OpB[(size_t)(qh * 64 + qt * 16 + quad * 4 + r) * C_ + cq * 32 + ct * 16 + col] =
              f2bf(Oacc[qt][ct][r]);
    #pragma unroll
    for (int qt = 0; qt < 2; ++qt) {
      float lsum = lacc[qt];
      lsum += __shfl_xor(lsum, 16, 64);
      lsum += __shfl_xor(lsum, 32, 64);
      if (quad == 0) lpart[(w * 2 + qt) * 16 + col] = lsum;
    }
    __syncthreads();
    if ((w & 1) == 0 && quad == 0) {
      #pragma unroll
      for (int qt = 0; qt < 2; ++qt) {
        int idx = b * N_ + n0 + (w >> 1) * 32 + qt * 16 + col;
        Lv[(size_t)sp * (B_ * N_) + idx] =
            lpart[(w * 2 + qt) * 16 + col] + lpart[((w + 1) * 2 + qt) * 16 + col];
      }
    }
  }
  grid_bar(bar);

  // ---------------- P3: merge(4 splits) + proj MFMA + residual ----------------
  {
    ushort* tile = sm_u;   // [32][HLD]
    const ushort* wpB = wB + 49152;
    int b = bx >> 7;
    int n0 = (bx & 127) * 32;
    {
      int n = tid >> 4, cc = tid & 15;   // 32 n x 16 cc
      int nIdx = b * N_ + n0 + n;
      float den = Lv[0 * (B_ * N_) + nIdx] + Lv[1 * (B_ * N_) + nIdx] +
                  Lv[2 * (B_ * N_) + nIdx] + Lv[3 * (B_ * N_) + nIdx];
      float inv = 1.f / den;
      float o[8];
      #pragma unroll
      for (int j = 0; j < 8; ++j) o[j] = 0.f;
      #pragma unroll
      for (int sp = 0; sp < NSPLIT; ++sp) {
        uint4 d = *(const uint4*)&Op[((size_t)sp * (B_ * N_) + nIdx) * C_ + cc * 8];
        unsigned dd[4] = {d.x, d.y, d.z, d.w};
        #pragma unroll
        for (int j = 0; j < 4; ++j) {
          o[j * 2]     += bf2f((ushort)(dd[j] & 0xFFFF));
          o[j * 2 + 1] += bf2f((ushort)(dd[j] >> 16));
        }
      }
      uint4 res;
      res.x = pkbf(o[1] * inv, o[0] * inv);
      res.y = pkbf(o[3] * inv, o[2] * inv);
      res.z = pkbf(o[5] * inv, o[4] * inv);
      res.w = pkbf(o[7] * inv, o[6] * inv);
      *(uint4*)&tile[n * HLD + cc * 8] = res;
    }
    __syncthreads();
    int o0 = w * 16;   // 8 waves x 16 output channels
    bf16x8 hf[2][4];
    #pragma unroll
    for (int nh = 0; nh < 2; ++nh)
      #pragma unroll
      for (int kc = 0; kc < 4; ++kc)
        hf[nh][kc] = *(const bf16x8*)&tile[(nh * 16 + col) * HLD + kc * 32 + quad * 8];
    floatx4 acc[2] = {(floatx4)0.f, (floatx4)0.f};
    #pragma unroll
    for (int kc = 0; kc < 4; ++kc) {
      int wo = (o0 + col) * C_ + kc * 32 + quad * 8;
      bf16x8 wf = *(const bf16x8*)&wpB[wo];
      #pragma unroll
      for (int nh = 0; nh < 2; ++nh)
        acc[nh] = __builtin_amdgcn_mfma_f32_16x16x32_bf16(wf, hf[nh][kc], acc[nh], 0, 0, 0);
    }
    float4 bpv = *(const float4*)&bp[o0 + quad * 4];
    float bb[4] = {bpv.x, bpv.y, bpv.z, bpv.w};
    #pragma unroll
    for (int nh = 0; nh < 2; ++nh)
      #pragma unroll
      for (int r = 0; r < 4; ++r) {
        size_t idx = ((size_t)b * C_ + o0 + quad * 4 + r) * N_ + n0 + nh * 16 + col;
        out[idx] = acc[nh][r] + bb[r] + x[idx];
      }
  }
}

extern "C" void kernel_launch(void* const* d_in, const int* in_sizes, int n_in,
                              void* d_out, int out_size, void* d_ws, size_t ws_size,
                              hipStream_t stream) {
  const float* x        = (const float*)d_in[0];
  const float* gn_scale = (const float*)d_in[1];
  const float* gn_bias  = (const float*)d_in[2];
  const float* wq = (const float*)d_in[3];
  const float* bq = (const float*)d_in[4];
  const float* wk = (const float*)d_in[5];
  const float* bk = (const float*)d_in[6];
  const float* wv = (const float*)d_in[7];
  const float* bv = (const float*)d_in[8];
  const float* wp = (const float*)d_in[9];
  const float* bp = (const float*)d_in[10];
  float* out = (float*)d_out;

  char* ws = (char*)d_ws;
  unsigned* bar = (unsigned*)ws;                 // barrier state (reset every replay)
  float*  Lv    = (float*)(ws + 262144);
  ushort* wB    = (ushort*)(ws + 524288);
  float*  gstat = (float*)(ws + 655360);
  ushort* qT    = (ushort*)(ws + (4u << 20));
  ushort* kT    = (ushort*)(ws + (8u << 20));
  ushort* vB    = (ushort*)(ws + (12u << 20));
  ushort* Op    = (ushort*)(ws + (16u << 20));

  hipMemsetAsync(bar, 0, 64, stream);
  fused_kernel<<<512, 512, 0, stream>>>(x, gn_scale, gn_bias, wq, bq, wk, bk,
                                        wv, bv, wp, bp, out, bar, Lv, wB, gstat,
                                        qT, kT, vB, Op);
}

// Round 9
// 276.332 us; speedup vs baseline: 1.3166x; 1.3166x over previous
//
#include <hip/hip_runtime.h>
#include <math.h>

#define B_ 4
#define C_ 128
#define N_ 4096
#define NSPLIT 4
#define MT 32     // keys per iteration
#define PLD 40    // Ps row stride (shorts): 32 + 8 pad (80 B, 16B-divisible)
#define HLD 136   // h/q/k tile row stride (shorts): 128 + 8 pad
#define VTLD 40   // v-tile row stride (shorts): 32 + 8 pad
#define NBLK 512u

typedef float floatx4 __attribute__((ext_vector_type(4)));
typedef short bf16x8 __attribute__((ext_vector_type(8)));

__device__ __forceinline__ ushort f2bf(float f) {  // RNE
  unsigned u = __float_as_uint(f);
  return (ushort)((u + 0x7FFF + ((u >> 16) & 1)) >> 16);
}
__device__ __forceinline__ float bf2f(ushort u) {
  return __uint_as_float(((unsigned)u) << 16);
}
__device__ __forceinline__ unsigned pkbf(float a, float b) {
  return __builtin_amdgcn_perm(__float_as_uint(a) + 0x8000u,
                               __float_as_uint(b) + 0x8000u, 0x07060302u);
}
__device__ __forceinline__ float fexp2(float x) {
#if __has_builtin(__builtin_amdgcn_exp2f)
  return __builtin_amdgcn_exp2f(x);
#else
  return exp2f(x);
#endif
}
__device__ __forceinline__ void gl2lds16(const ushort* g, ushort* l) {
  __builtin_amdgcn_global_load_lds(
      (const __attribute__((address_space(1))) void*)g,
      (__attribute__((address_space(3))) void*)l, 16, 0, 0);
}

// Two-level software grid barrier, monotonic generations (phase = 1,2,3).
// R8's flat barrier was correct but cost ~77us/barrier: 512 agent-scope RMWs
// serialized on ONE cacheline at cross-XCD latency.  Fix: 8 leaf counters on
// separate cachelines (leaf = bx&7 -> same-XCD group under round-robin dispatch;
// 64 arrivals each, in parallel), leaf-completers RMW a root counter (8 arrivals),
// root-completer release-stores the generation.  HB chain: block writes ->
// leaf RMW(acq_rel) -> leaf-completer -> root RMW(acq_rel) -> root-completer ->
// gen store(release) -> spinner gen load(acquire).  Same proven ordering as R8.
// Layout (uint idx): [0]=gen, [16]=root count, [32+leaf*16]=leaf counts.
__device__ __forceinline__ void grid_bar(unsigned* bar, unsigned phase) {
  __syncthreads();
  if (threadIdx.x == 0) {
    unsigned* lc = &bar[32 + (blockIdx.x & 7) * 16];
    unsigned prev = __hip_atomic_fetch_add(lc, 1u, __ATOMIC_ACQ_REL, __HIP_MEMORY_SCOPE_AGENT);
    if (prev + 1u == phase * (NBLK / 8u)) {
      unsigned rprev = __hip_atomic_fetch_add(&bar[16], 1u, __ATOMIC_ACQ_REL, __HIP_MEMORY_SCOPE_AGENT);
      if (rprev + 1u == phase * 8u)
        __hip_atomic_store(&bar[0], phase, __ATOMIC_RELEASE, __HIP_MEMORY_SCOPE_AGENT);
    }
    while (__hip_atomic_load(&bar[0], __ATOMIC_ACQUIRE, __HIP_MEMORY_SCOPE_AGENT) < phase)
      __builtin_amdgcn_s_sleep(16);
  }
  __syncthreads();
}

// =====================================================================================
// ONE kernel, 4 phases separated by two-level software grid barriers.
// grid 512 x 512 thr, 54,272 B LDS (attn footprint; overlaid per phase),
// launch_bounds(512,4) -> exactly 2 blocks/CU x 256 CU co-resident.
// Phase roles per block (bx = 0..511):
//   P0: bx<256 -> gn-stats task (b,g,part); bx>=256 -> weight bf16 convert.
//   P1: gnqkv, (b, 32-n tile) = (bx>>7, bx&127).  8 waves x 16 out-ch.
//   P2: attn (R3/R6-identical structure), sp=bx&3, qblk=(bx>>2)&31, b=bx>>7.
//   P3: mergeproj, (b, 32-n tile).  8 waves x 16 out-ch.
// =====================================================================================
__global__ __launch_bounds__(512, 4) void fused_kernel(
    const float* __restrict__ x, const float* __restrict__ gn_scale,
    const float* __restrict__ gn_bias,
    const float* __restrict__ wq, const float* __restrict__ bq,
    const float* __restrict__ wk, const float* __restrict__ bk,
    const float* __restrict__ wv, const float* __restrict__ bv,
    const float* __restrict__ wp, const float* __restrict__ bp,
    float* __restrict__ out, unsigned* __restrict__ bar,
    float* __restrict__ Lv, ushort* __restrict__ wB,
    float* __restrict__ gstat, ushort* __restrict__ qT, ushort* __restrict__ kT,
    ushort* __restrict__ vB, ushort* __restrict__ Op) {
  __shared__ __align__(16) char smem[54272];
  ushort* sm_u = (ushort*)smem;
  int bx = blockIdx.x;
  int tid = threadIdx.x, lane = tid & 63, w = tid >> 6;
  int col = lane & 15, quad = lane >> 4;

  // ---------------- P0: gn stats + weight convert ----------------
  if (bx >= 256) {   // weight convert: 65536 elems over 256 blocks
    if (tid < 256) {
      int i = (bx - 256) * 256 + tid;
      int m = i >> 14, j = i & 16383;
      const float* src = (m == 0) ? wq : (m == 1) ? wk : (m == 2) ? wv : wp;
      wB[i] = f2bf(src[j]);
    }
  } else {
    int b = bx >> 6, g = (bx >> 3) & 7, part = bx & 7;
    const float4* xp = (const float4*)(x + (size_t)(b * C_ + g * 16) * N_) + part * 2048;
    float s = 0.f, ss = 0.f;
    for (int i = tid; i < 2048; i += 512) {
      float4 v = xp[i];
      s += v.x + v.y + v.z + v.w;
      ss += v.x * v.x + v.y * v.y + v.z * v.z + v.w * v.w;
    }
    #pragma unroll
    for (int o = 32; o > 0; o >>= 1) {
      s += __shfl_down(s, o, 64);
      ss += __shfl_down(ss, o, 64);
    }
    float* rs = (float*)smem;        // 8 floats
    float* rss = (float*)smem + 8;   // 8 floats
    if (lane == 0) { rs[w] = s; rss[w] = ss; }
    __syncthreads();
    if (tid == 0) {
      float S = 0.f, SS = 0.f;
      #pragma unroll
      for (int k = 0; k < 8; ++k) { S += rs[k]; SS += rss[k]; }
      int slot = (b * 8 + g) * 8 + part;
      gstat[slot]       = S;
      gstat[256 + slot] = SS;
    }
  }
  grid_bar(bar, 1u);

  // ---------------- P1: GN-apply + QKV MFMA ----------------
  {
    ushort* hs = sm_u;               // [32][HLD]   8704 B
    ushort* Qt = sm_u + 4352;        // [32][HLD]
    ushort* Kt = sm_u + 8704;        // [32][HLD]
    ushort* Vt = sm_u + 13056;       // [128][VTLD] 10240 B
    float* sSc = (float*)(smem + 36352);
    float* sBi = (float*)(smem + 36864);
    int b = bx >> 7;
    int n0 = (bx & 127) * 32;
    if (tid < 128) {
      int g = tid >> 4;
      float S = 0.f, SS = 0.f;
      #pragma unroll
      for (int p = 0; p < 8; ++p) {
        S  += gstat[(b * 8 + g) * 8 + p];
        SS += gstat[256 + (b * 8 + g) * 8 + p];
      }
      float mu = S * (1.f / 65536.f);
      float var = SS * (1.f / 65536.f) - mu * mu;
      float rstd = rsqrtf(var + 1e-6f);
      float sc = gn_scale[tid] * rstd;
      sSc[tid] = sc;
      sBi[tid] = gn_bias[tid] - mu * sc;
    }
    __syncthreads();
    #pragma unroll
    for (int k2 = 0; k2 < 2; ++k2) {   // 128 c x 8 float4 (32 n) = 1024
      int i = tid + k2 * 512;
      int c = i >> 3, n4 = i & 7;
      float4 v = *(const float4*)(x + (size_t)(b * C_ + c) * N_ + n0 + n4 * 4);
      float sc = sSc[c], bi = sBi[c];
      hs[(n4 * 4 + 0) * HLD + c] = f2bf(v.x * sc + bi);
      hs[(n4 * 4 + 1) * HLD + c] = f2bf(v.y * sc + bi);
      hs[(n4 * 4 + 2) * HLD + c] = f2bf(v.z * sc + bi);
      hs[(n4 * 4 + 3) * HLD + c] = f2bf(v.w * sc + bi);
    }
    __syncthreads();
    int o0 = w * 16;   // 8 waves x 16 output channels
    bf16x8 hf[2][4];   // [n-half][kc]
    #pragma unroll
    for (int nh = 0; nh < 2; ++nh)
      #pragma unroll
      for (int kc = 0; kc < 4; ++kc)
        hf[nh][kc] = *(const bf16x8*)&hs[(nh * 16 + col) * HLD + kc * 32 + quad * 8];
    const ushort* Wq = wB;
    const ushort* Wk = wB + 16384;
    const ushort* Wv = wB + 32768;
    const float scl = 0.12751879752224991f;  // 128^-0.5 * log2(e)
    floatx4 aq[2] = {(floatx4)0.f, (floatx4)0.f};
    floatx4 ak[2] = {(floatx4)0.f, (floatx4)0.f};
    floatx4 av[2] = {(floatx4)0.f, (floatx4)0.f};
    #pragma unroll
    for (int kc = 0; kc < 4; ++kc) {
      int wo = (o0 + col) * C_ + kc * 32 + quad * 8;
      bf16x8 wqf = *(const bf16x8*)&Wq[wo];
      bf16x8 wkf = *(const bf16x8*)&Wk[wo];
      bf16x8 wvf = *(const bf16x8*)&Wv[wo];
      #pragma unroll
      for (int nh = 0; nh < 2; ++nh) {
        aq[nh] = __builtin_amdgcn_mfma_f32_16x16x32_bf16(wqf, hf[nh][kc], aq[nh], 0, 0, 0);
        ak[nh] = __builtin_amdgcn_mfma_f32_16x16x32_bf16(wkf, hf[nh][kc], ak[nh], 0, 0, 0);
        av[nh] = __builtin_amdgcn_mfma_f32_16x16x32_bf16(wvf, hf[nh][kc], av[nh], 0, 0, 0);
      }
    }
    float4 bqv = *(const float4*)&bq[o0 + quad * 4];
    float4 bkv = *(const float4*)&bk[o0 + quad * 4];
    float4 bvv = *(const float4*)&bv[o0 + quad * 4];
    #pragma unroll
    for (int nh = 0; nh < 2; ++nh) {
      uint2 qs = { pkbf((aq[nh][1] + bqv.y) * scl, (aq[nh][0] + bqv.x) * scl),
                   pkbf((aq[nh][3] + bqv.w) * scl, (aq[nh][2] + bqv.z) * scl) };
      uint2 ks = { pkbf(ak[nh][1] + bkv.y, ak[nh][0] + bkv.x),
                   pkbf(ak[nh][3] + bkv.w, ak[nh][2] + bkv.z) };
      *(uint2*)&Qt[(nh * 16 + col) * HLD + o0 + quad * 4] = qs;
      *(uint2*)&Kt[(nh * 16 + col) * HLD + o0 + quad * 4] = ks;
      float vv[4] = {av[nh][0] + bvv.x, av[nh][1] + bvv.y,
                     av[nh][2] + bvv.z, av[nh][3] + bvv.w};
      #pragma unroll
      for (int r = 0; r < 4; ++r)
        Vt[(o0 + quad * 4 + r) * VTLD + nh * 16 + col] = f2bf(vv[r]);
    }
    __syncthreads();
    {
      int row = tid >> 4, seg = tid & 15;   // 32 rows x 16 segs
      size_t dst = ((size_t)b * N_ + n0 + row) * C_ + seg * 8;
      *(uint4*)(qT + dst) = *(const uint4*)&Qt[row * HLD + seg * 8];
      *(uint4*)(kT + dst) = *(const uint4*)&Kt[row * HLD + seg * 8];
    }
    {
      int o = tid >> 2, seg = tid & 3;      // 128 ch x 4 segs
      *(uint4*)(vB + ((size_t)b * C_ + o) * N_ + n0 + seg * 8) =
          *(const uint4*)&Vt[o * VTLD + seg * 8];
    }
  }
  grid_bar(bar, 2u);

  // ---------------- P2: flash attention (R3/R6 structure, flat LDS) ----------------
  {
    ushort* Ks = sm_u;            // [2][4096] shorts (chunk-swizzled by row&7)
    ushort* Vs = sm_u + 8192;     // [2][4096] shorts (chunk-swizzled by (c>>1)&3)
    ushort* Ps = sm_u + 16384;    // [2][5120] shorts, double-buffered
    float* lpart = (float*)(smem + 53248);  // [8][2][16]
    int sp = bx & 3;
    int qblk = (bx >> 2) & 31;
    int b = bx >> 7;
    int n0 = qblk * 128;
    int wu = __builtin_amdgcn_readfirstlane(w);
    int mtw = w & 1, qg = w >> 1;   // S-phase roles
    int qh = w & 1, cq = w >> 1;    // PV-phase roles
    const ushort* kTb = kT + (size_t)b * N_ * C_;
    const ushort* vBb = vB + (size_t)b * C_ * N_;

    bf16x8 qf[2][4];
    #pragma unroll
    for (int qt = 0; qt < 2; ++qt)
      #pragma unroll
      for (int kc = 0; kc < 4; ++kc)
        qf[qt][kc] = *(const bf16x8*)(qT + ((size_t)b * N_ + n0 + qg * 32 + qt * 16 + col) * C_ + kc * 32 + quad * 8);

    floatx4 Oacc[4][2];
    #pragma unroll
    for (int qt = 0; qt < 4; ++qt)
      #pragma unroll
      for (int ct = 0; ct < 2; ++ct) Oacc[qt][ct] = (floatx4)0.f;
    float lacc[2] = {0.f, 0.f};

    const int m00 = sp * 1024;
    const ushort* kgp;
    const ushort* vgp;
    {
      int r = wu * 4 + (lane >> 4);
      int pos = (lane & 15) ^ (r & 7);
      kgp = kTb + (size_t)(m00 + r) * 128 + pos * 8;
      int c = wu * 16 + (lane >> 2);
      int mc = (lane & 3) ^ ((lane >> 3) & 3);
      vgp = vBb + (size_t)c * N_ + m00 + mc * 8;
    }

    #define STAGE(buf)                                        \
      {                                                       \
        gl2lds16(kgp, Ks + (buf)*4096 + wu * 512);            \
        gl2lds16(vgp, Vs + (buf)*4096 + wu * 512);            \
        kgp += MT * 128;                                      \
        vgp += MT;                                            \
      }

    #define S_COMPUTE(KsB, st)                                                          \
      {                                                                                 \
        int row = mtw * 16 + col;                                                       \
        bf16x8 kf[4];                                                                   \
        _Pragma("unroll")                                                               \
        for (int kc = 0; kc < 4; ++kc)                                                  \
          kf[kc] = *(const bf16x8*)&(KsB)[row * 128 + (((4 * kc + quad) ^ (col & 7)) * 8)]; \
        __builtin_amdgcn_s_setprio(1);                                                  \
        _Pragma("unroll")                                                               \
        for (int qt = 0; qt < 2; ++qt) {                                                \
          floatx4 acc = (floatx4)0.f;                                                   \
          _Pragma("unroll")                                                             \
          for (int kc = 0; kc < 4; ++kc)                                                \
            acc = __builtin_amdgcn_mfma_f32_16x16x32_bf16(kf[kc], qf[qt][kc], acc, 0, 0, 0); \
          st[qt] = acc;                                                                 \
        }                                                                               \
        __builtin_amdgcn_s_setprio(0);                                                  \
      }

    #define SOFTMAX_WRITE(PsB, st)                                                      \
      {                                                                                 \
        _Pragma("unroll")                                                               \
        for (int qt = 0; qt < 2; ++qt) {                                                \
          int prow = (qg * 32 + qt * 16 + col) * PLD + mtw * 16;                        \
          float p0 = fexp2(st[qt][0]);                                                  \
          float p1 = fexp2(st[qt][1]);                                                  \
          float p2 = fexp2(st[qt][2]);                                                  \
          float p3 = fexp2(st[qt][3]);                                                  \
          uint2 pk = { pkbf(p1, p0), pkbf(p3, p2) };                                    \
          *(uint2*)&(PsB)[prow + quad * 4] = pk;                                        \
          lacc[qt] += (p0 + p1) + (p2 + p3);                                            \
        }                                                                               \
      }

    #define V_LOAD(VsB, vfp)                                                            \
      {                                                                                 \
        _Pragma("unroll")                                                               \
        for (int ct = 0; ct < 2; ++ct)                                                  \
          vfp[ct] = *(const bf16x8*)&(VsB)[(cq * 32 + ct * 16 + col) * MT +             \
                                           ((quad ^ ((col >> 1) & 3)) * 8)];            \
      }

    #define PV_COMPUTE(PsB, vfp)                                                        \
      {                                                                                 \
        __builtin_amdgcn_s_setprio(1);                                                  \
        _Pragma("unroll")                                                               \
        for (int qt = 0; qt < 4; ++qt) {                                                \
          bf16x8 pf = *(const bf16x8*)&(PsB)[(qh * 64 + qt * 16 + col) * PLD + quad * 8]; \
          _Pragma("unroll")                                                             \
          for (int ct = 0; ct < 2; ++ct)                                                \
            Oacc[qt][ct] = __builtin_amdgcn_mfma_f32_16x16x32_bf16(pf, vfp[ct], Oacc[qt][ct], 0, 0, 0); \
        }                                                                               \
        __builtin_amdgcn_s_setprio(0);                                                  \
      }

    floatx4 st[2];
    bf16x8 vfp[2];

    STAGE(0);
    __syncthreads();

    // t = 0 (no PV yet)
    STAGE(1);
    S_COMPUTE(Ks, st);
    SOFTMAX_WRITE(Ps, st);
    V_LOAD(Vs, vfp);
    __syncthreads();

    // steady state t = 1..30: S(t) ; PV(t-1) ; softmax(t) ; vload(t) ; barrier
    for (int t = 1; t < 31; ++t) {
      STAGE((t + 1) & 1);
      S_COMPUTE(Ks + (t & 1) * 4096, st);
      PV_COMPUTE(Ps + ((t - 1) & 1) * 5120, vfp);
      SOFTMAX_WRITE(Ps + (t & 1) * 5120, st);
      V_LOAD(Vs + (t & 1) * 4096, vfp);
      __syncthreads();
    }

    // t = 31 (no stage)
    S_COMPUTE(Ks + 4096, st);
    PV_COMPUTE(Ps, vfp);
    SOFTMAX_WRITE(Ps + 5120, st);
    V_LOAD(Vs + 4096, vfp);
    __syncthreads();

    // drain PV(31)
    PV_COMPUTE(Ps + 5120, vfp);

    // epilogue: Op[sp][b][n][c] bf16 (unnormalized)
    ushort* OpB = Op + (((size_t)sp * B_ + b) * N_ + n0) * C_;
    #pragma unroll
    for (int qt = 0; qt < 4; ++qt)
      #pragma unroll
      for (int ct = 0; ct < 2; ++ct)
        #pragma unroll
        for (int r = 0; r < 4; ++r)
          OpB[(size_t)(qh * 64 + qt * 16 + quad * 4 + r) * C_ + cq * 32 + ct * 16 + col] =
              f2bf(Oacc[qt][ct][r]);
    #pragma unroll
    for (int qt = 0; qt < 2; ++qt) {
      float lsum = lacc[qt];
      lsum += __shfl_xor(lsum, 16, 64);
      lsum += __shfl_xor(lsum, 32, 64);
      if (quad == 0) lpart[(w * 2 + qt) * 16 + col] = lsum;
    }
    __syncthreads();
    if ((w & 1) == 0 && quad == 0) {
      #pragma unroll
      for (int qt = 0; qt < 2; ++qt) {
        int idx = b * N_ + n0 + (w >> 1) * 32 + qt * 16 + col;
        Lv[(size_t)sp * (B_ * N_) + idx] =
            lpart[(w * 2 + qt) * 16 + col] + lpart[((w + 1) * 2 + qt) * 16 + col];
      }
    }
  }
  grid_bar(bar, 3u);

  // ---------------- P3: merge(4 splits) + proj MFMA + residual ----------------
  {
    ushort* tile = sm_u;   // [32][HLD]
    const ushort* wpB = wB + 49152;
    int b = bx >> 7;
    int n0 = (bx & 127) * 32;
    {
      int n = tid >> 4, cc = tid & 15;   // 32 n x 16 cc
      int nIdx = b * N_ + n0 + n;
      float den = Lv[0 * (B_ * N_) + nIdx] + Lv[1 * (B_ * N_) + nIdx] +
                  Lv[2 * (B_ * N_) + nIdx] + Lv[3 * (B_ * N_) + nIdx];
      float inv = 1.f / den;
      float o[8];
      #pragma unroll
      for (int j = 0; j < 8; ++j) o[j] = 0.f;
      #pragma unroll
      for (int sp = 0; sp < NSPLIT; ++sp) {
        uint4 d = *(const uint4*)&Op[((size_t)sp * (B_ * N_) + nIdx) * C_ + cc * 8];
        unsigned dd[4] = {d.x, d.y, d.z, d.w};
        #pragma unroll
        for (int j = 0; j < 4; ++j) {
          o[j * 2]     += bf2f((ushort)(dd[j] & 0xFFFF));
          o[j * 2 + 1] += bf2f((ushort)(dd[j] >> 16));
        }
      }
      uint4 res;
      res.x = pkbf(o[1] * inv, o[0] * inv);
      res.y = pkbf(o[3] * inv, o[2] * inv);
      res.z = pkbf(o[5] * inv, o[4] * inv);
      res.w = pkbf(o[7] * inv, o[6] * inv);
      *(uint4*)&tile[n * HLD + cc * 8] = res;
    }
    __syncthreads();
    int o0 = w * 16;   // 8 waves x 16 output channels
    bf16x8 hf[2][4];
    #pragma unroll
    for (int nh = 0; nh < 2; ++nh)
      #pragma unroll
      for (int kc = 0; kc < 4; ++kc)
        hf[nh][kc] = *(const bf16x8*)&tile[(nh * 16 + col) * HLD + kc * 32 + quad * 8];
    floatx4 acc[2] = {(floatx4)0.f, (floatx4)0.f};
    #pragma unroll
    for (int kc = 0; kc < 4; ++kc) {
      int wo = (o0 + col) * C_ + kc * 32 + quad * 8;
      bf16x8 wf = *(const bf16x8*)&wpB[wo];
      #pragma unroll
      for (int nh = 0; nh < 2; ++nh)
        acc[nh] = __builtin_amdgcn_mfma_f32_16x16x32_bf16(wf, hf[nh][kc], acc[nh], 0, 0, 0);
    }
    float4 bpv = *(const float4*)&bp[o0 + quad * 4];
    float bb[4] = {bpv.x, bpv.y, bpv.z, bpv.w};
    #pragma unroll
    for (int nh = 0; nh < 2; ++nh)
      #pragma unroll
      for (int r = 0; r < 4; ++r) {
        size_t idx = ((size_t)b * C_ + o0 + quad * 4 + r) * N_ + n0 + nh * 16 + col;
        out[idx] = acc[nh][r] + bb[r] + x[idx];
      }
  }
}

extern "C" void kernel_launch(void* const* d_in, const int* in_sizes, int n_in,
                              void* d_out, int out_size, void* d_ws, size_t ws_size,
                              hipStream_t stream) {
  const float* x        = (const float*)d_in[0];
  const float* gn_scale = (const float*)d_in[1];
  const float* gn_bias  = (const float*)d_in[2];
  const float* wq = (const float*)d_in[3];
  const float* bq = (const float*)d_in[4];
  const float* wk = (const float*)d_in[5];
  const float* bk = (const float*)d_in[6];
  const float* wv = (const float*)d_in[7];
  const float* bv = (const float*)d_in[8];
  const float* wp = (const float*)d_in[9];
  const float* bp = (const float*)d_in[10];
  float* out = (float*)d_out;

  char* ws = (char*)d_ws;
  unsigned* bar = (unsigned*)ws;                 // barrier state (reset every replay)
  float*  Lv    = (float*)(ws + 262144);
  ushort* wB    = (ushort*)(ws + 524288);
  float*  gstat = (float*)(ws + 655360);
  ushort* qT    = (ushort*)(ws + (4u << 20));
  ushort* kT    = (ushort*)(ws + (8u << 20));
  ushort* vB    = (ushort*)(ws + (12u << 20));
  ushort* Op    = (ushort*)(ws + (16u << 20));

  hipMemsetAsync(bar, 0, 1024, stream);
  fused_kernel<<<512, 512, 0, stream>>>(x, gn_scale, gn_bias, wq, bq, wk, bk,
                                        wv, bv, wp, bp, out, bar, Lv, wB, gstat,
                                        qT, kT, vB, Op);
}